// Round 1
// baseline (294.603 us; speedup 1.0000x reference)
//
#include <hip/hip_runtime.h>

// TaylorExp feature map, d=16:
//   out[row, 0]            = 1
//   out[row, 1..16]        = x[row, i] * 0.5                      (1/rrd, rrd=sqrt(sqrt(16))=2)
//   out[row, 17 + i*16 + j] = x[row,i]*x[row,j] * (1/(4*sqrt(2)))  (/sqrt(2) then /sqrt(d)=4)
//
// Memory-bound (writes ~17x reads). Strategy: block of 256 threads handles 16
// rows; stage 16x16 fp32 tile in LDS (one coalesced 1KB load), then write the
// block's contiguous 4368-float output chunk as float4 stores.

#define D               16
#define OUTD            273          // 1 + 16 + 256
#define ROWS_PER_BLOCK  16
#define THREADS         256
#define CHUNK           (OUTD * ROWS_PER_BLOCK)   // 4368 floats per block
#define CHUNK4          (CHUNK / 4)               // 1092 float4 per block

__global__ __launch_bounds__(THREADS)
void taylor_exp_kernel(const float* __restrict__ x,
                       float* __restrict__ out,
                       int nrows) {
    __shared__ float xs[ROWS_PER_BLOCK * D];   // 1 KB

    const int tid = threadIdx.x;
    const long long rowBase = (long long)blockIdx.x * ROWS_PER_BLOCK;

    // Stage 16 rows x 16 floats, one element per thread (coalesced 1KB).
    {
        const int localRow = tid >> 4;  // tid / D
        float v = 0.0f;
        if (rowBase + localRow < (long long)nrows) {
            v = x[rowBase * D + tid];
        }
        xs[tid] = v;
    }
    __syncthreads();

    const float S2 = 0.17677669529663688f;  // 1/(4*sqrt(2))
    const long long outBase = rowBase * OUTD;
    const long long totalOut = (long long)nrows * OUTD;

    for (int t = tid; t < CHUNK4; t += THREADS) {
        const int g = t * 4;                 // element offset inside block chunk
        int row = g / OUTD;                  // compiler emits magic-multiply
        const int k0 = g - row * OUTD;

        float vals[4];
#pragma unroll
        for (int e = 0; e < 4; ++e) {
            int kk = k0 + e;
            int r = row;
            if (kk >= OUTD) { kk -= OUTD; r += 1; }   // at most one wrap (e<4)
            float val;
            if (kk == 0) {
                val = 1.0f;
            } else if (kk <= D) {
                val = xs[r * D + (kk - 1)] * 0.5f;
            } else {
                const int t2 = kk - (D + 1);
                val = xs[r * D + (t2 >> 4)] * xs[r * D + (t2 & 15)] * S2;
            }
            vals[e] = val;
        }

        const long long gi = outBase + g;
        if (gi + 4 <= totalOut) {
            float4 o = make_float4(vals[0], vals[1], vals[2], vals[3]);
            *reinterpret_cast<float4*>(out + gi) = o;
        } else {
            // ragged tail (only if nrows % ROWS_PER_BLOCK != 0)
            for (int e = 0; e < 4; ++e) {
                if (gi + e < totalOut) out[gi + e] = vals[e];
            }
        }
    }
}

extern "C" void kernel_launch(void* const* d_in, const int* in_sizes, int n_in,
                              void* d_out, int out_size, void* d_ws, size_t ws_size,
                              hipStream_t stream) {
    const float* x = (const float*)d_in[0];
    float* out = (float*)d_out;

    const int n = in_sizes[0];        // total x elements
    const int nrows = n / D;          // 262144 for the bench shape
    const int blocks = (nrows + ROWS_PER_BLOCK - 1) / ROWS_PER_BLOCK;

    taylor_exp_kernel<<<dim3(blocks), dim3(THREADS), 0, stream>>>(x, out, nrows);
}